// Round 1
// baseline (214.168 us; speedup 1.0000x reference)
//
#include <hip/hip_runtime.h>
#include <math.h>

// N=100000 nodes, E=1000000 edges, D_IN=64, D_MODEL=64, H=4 x D=16.
// Packed node layout: per node, 16 chunks of 16 B; chunk c = bytes [16c,16c+16)
//   = { q[4c..4c+3] fp16 (8 B) | v[4c..4c+3] fp16 (8 B) }. Row = 256 B.

typedef _Float16 h2 __attribute__((ext_vector_type(2)));
typedef _Float16 half8 __attribute__((ext_vector_type(8)));
typedef float floatx4 __attribute__((ext_vector_type(4)));

#define SP_ROW 136  // fp16 per LDS row (272 B): +8 pad breaks pow-2 bank stride

// ---------------------------------------------------------------------------
// Kernel 0: prep. Blocks [0,32): Wt[n][k] = fp16 W[k][n] (n<64 -> Wqk col n,
// else Wv col n-64). Blocks [32,..): CSR rowptr binary search.  (UNCHANGED)
__global__ __launch_bounds__(256) void mhga_prep(
    const float* __restrict__ Wqk, const float* __restrict__ Wv,
    _Float16* __restrict__ Wt,
    const int* __restrict__ receivers, int* __restrict__ row_ptr,
    int N, int E)
{
    if ((int)blockIdx.x < 32) {
        const int idx = blockIdx.x * 256 + threadIdx.x;   // 0..8191
        const int n = idx >> 6, k = idx & 63;
        const float w = (n < 64) ? Wqk[k * 64 + n] : Wv[k * 64 + (n - 64)];
        Wt[idx] = (_Float16)w;
        return;
    }
    const int n = (blockIdx.x - 32) * 256 + threadIdx.x;
    if (n > N) return;
    int lo = 0, hi = E;
    while (lo < hi) {
        const int mid = (lo + hi) >> 1;
        if (receivers[mid] < n) lo = mid + 1; else hi = mid;
    }
    row_ptr[n] = lo;
}

// ---------------------------------------------------------------------------
// Kernel 1: MFMA fp16 projection -> packed fp16 q|v rows.  (UNCHANGED — control)
__global__ __launch_bounds__(256) void mhga_proj(
    const float* __restrict__ X, const _Float16* __restrict__ Wt,
    const float* __restrict__ bqk, const float* __restrict__ bv,
    unsigned char* __restrict__ packed, int N)
{
    __shared__ __align__(16) _Float16 sP[64 * SP_ROW];   // 17 KB repack tile
    const int t = threadIdx.x;
    const int w = t >> 6, lane = t & 63;
    const int ln = lane & 15, quad = lane >> 4;
    const int m0 = blockIdx.x * 64;

    // A fragments: A[m=ln][k=quad*8+j], k-halves 0 / 32. Direct f32 loads.
    const int arow = min(m0 + w * 16 + ln, N - 1);
    const float* xr = X + (size_t)arow * 64;
    const float4 xa = *(const float4*)(xr + quad * 8);
    const float4 xb = *(const float4*)(xr + quad * 8 + 4);
    const float4 xc = *(const float4*)(xr + 32 + quad * 8);
    const float4 xd = *(const float4*)(xr + 32 + quad * 8 + 4);
    const half8 a0 = { (_Float16)xa.x, (_Float16)xa.y, (_Float16)xa.z,
                       (_Float16)xa.w, (_Float16)xb.x, (_Float16)xb.y,
                       (_Float16)xb.z, (_Float16)xb.w };
    const half8 a1 = { (_Float16)xc.x, (_Float16)xc.y, (_Float16)xc.z,
                       (_Float16)xc.w, (_Float16)xd.x, (_Float16)xd.y,
                       (_Float16)xd.z, (_Float16)xd.w };

    // 8 output tiles: B[k][n], lane&15 = n-within-tile, k = quad*8+j.
    floatx4 acc[8];
#pragma unroll
    for (int tt = 0; tt < 8; ++tt) {
        const _Float16* wrow = Wt + (tt * 16 + ln) * 64;
        const half8 b0 = *(const half8*)(wrow + quad * 8);
        const half8 b1 = *(const half8*)(wrow + 32 + quad * 8);
        floatx4 c = {0.f, 0.f, 0.f, 0.f};
        c = __builtin_amdgcn_mfma_f32_16x16x32_f16(a0, b0, c, 0, 0, 0);
        c = __builtin_amdgcn_mfma_f32_16x16x32_f16(a1, b1, c, 0, 0, 0);
        acc[tt] = c;
    }

    // Repack: D row = quad*4+reg, col j = tt*16+ln. q col j -> fp16 idx
    // (j>>2)*8 + (j&3); v col j -> (j>>2)*8 + 4 + (j&3).
#pragma unroll
    for (int tt = 0; tt < 8; ++tt) {
        const float bt = (tt < 4) ? bqk[tt * 16 + ln] : bv[(tt - 4) * 16 + ln];
        const int j = (tt & 3) * 16 + ln;
        const int fidx = (j >> 2) * 8 + ((tt < 4) ? 0 : 4) + (j & 3);
#pragma unroll
        for (int r = 0; r < 4; ++r) {
            const int lrow = w * 16 + quad * 4 + r;
            sP[lrow * SP_ROW + fidx] = (_Float16)(acc[tt][r] + bt);
        }
    }

    // Wave-local coalesced copy: lane lt -> row w*16+(lt>>2), 64-B segment
    // (lt&3). In-order DS completion + compiler lgkmcnt ordering make the
    // write->read dependency safe within the wave (no barrier).
    const int crow = w * 16 + (lane >> 2);
    const int grow = m0 + crow;
    if (grow < N) {
        const _Float16* src = sP + crow * SP_ROW + (lane & 3) * 32;
        unsigned char* dst = packed + (size_t)grow * 256 + (lane & 3) * 64;
#pragma unroll
        for (int c = 0; c < 4; ++c)
            *(uint4*)(dst + c * 16) = *(const uint4*)(src + c * 8);
    }
}

// ---------------------------------------------------------------------------
// Kernel 2: fused attention + output projection — REWRITTEN this round.
//  * 8 edge-groups x 8 lanes (was 4 x 16): lane u=lane&7 owns channels
//    8u..8u+7 (two 16-B chunks, 32 B/lane). 8 random-row gathers in flight
//    per wave (2x MLP), half the wave-instructions per edge. A head's 16
//    channels live on a lane PAIR -> single shfl_xor(d,1) score reduce.
//  * Single-pass softmax: deg<=64 (always, Poisson(10) data) -> each lane
//    caches its <=8 p values in statically-indexed VGPRs, computes l, then
//    writes attn_out already normalized. No p_ws buffer, no vmcnt(0) drain,
//    no volatile reload, no pass B. (-32 MB HBM round-trip, -per-lap stall.)
//  * deg>64 fallback (never taken for this data, kept for correctness):
//    two-pass recompute of the gathers+dots; no global scratch needed.
// Gathers in the hot loop are unconditional (tail slots clamp to row 0 via
// sid=0; p zeroed by cndmask) -> branch-free unrolled body the compiler can
// pipeline.
__global__ __launch_bounds__(256) void mhga_attn(
    const unsigned char* __restrict__ packed,
    const int* __restrict__ senders, const int* __restrict__ row_ptr,
    const float* __restrict__ Wout, const float* __restrict__ bout,
    float* __restrict__ out, float* __restrict__ attn_out, int N)
{
    __shared__ float sW[64 * 64];    // Wout[k][j]
    __shared__ float sCtx[4][64];    // per-wave normalized ctx (wave-private)
    const int t = threadIdx.x;
#pragma unroll
    for (int i = t * 4; i < 4096; i += 1024)
        *(float4*)(sW + i) = *(const float4*)(Wout + i);

    const int wave = t >> 6, lane = t & 63;
    const int g = lane >> 3, u = lane & 7;   // edge-group, channel-octet
    const float bo = bout[lane];
    __syncthreads();   // the ONLY block-wide barrier

    for (int n = blockIdx.x * 4 + wave; n < N; n += gridDim.x * 4) {
        const int e0 = row_ptr[n];
        const int e1 = row_ptr[n + 1];
        const int cnt = e1 - e0;

        // Receiver q, channels 8u..8u+7 (chunks 2u, 2u+1).
        const unsigned char* qrow = packed + (size_t)n * 256 + u * 32;
        const uint4 qA = *(const uint4*)(qrow);
        const uint4 qB = *(const uint4*)(qrow + 16);
        const h2 q0 = __builtin_bit_cast(h2, qA.x);
        const h2 q1 = __builtin_bit_cast(h2, qA.y);
        const h2 q2 = __builtin_bit_cast(h2, qB.x);
        const h2 q3 = __builtin_bit_cast(h2, qB.y);

        float l = 0.f;
        float ctx[8] = {0.f, 0.f, 0.f, 0.f, 0.f, 0.f, 0.f, 0.f};
        float preg[8];
        int iters = 0;

        if (cnt <= 64) {
            // ---- hot path: one 64-edge chunk, p cached in registers ----
            int sid = 0;
            if (e0 + lane < e1) sid = senders[e0 + lane];   // coalesced
            iters = (cnt + 7) >> 3;
#pragma unroll
            for (int i = 0; i < 8; ++i) {
                if (i >= iters) break;                       // wave-uniform
                const int idx = i * 8 + g;
                const int s = __shfl(sid, idx, 64);          // row 0 if tail
                const unsigned char* row = packed + (size_t)s * 256 + u * 32;
                const uint4 A = *(const uint4*)(row);
                const uint4 B = *(const uint4*)(row + 16);
                float d = __builtin_amdgcn_fdot2(q0, __builtin_bit_cast(h2, A.x), 0.f, false);
                d = __builtin_amdgcn_fdot2(q1, __builtin_bit_cast(h2, A.y), d, false);
                d = __builtin_amdgcn_fdot2(q2, __builtin_bit_cast(h2, B.x), d, false);
                d = __builtin_amdgcn_fdot2(q3, __builtin_bit_cast(h2, B.y), d, false);
                d += __shfl_xor(d, 1, 64);                   // head pair reduce
                float p = __expf(d);
                p = (idx < cnt) ? p : 0.f;                   // cndmask, no branch
                preg[i] = p;
                l += p;
                const h2 vA0 = __builtin_bit_cast(h2, A.z);
                const h2 vA1 = __builtin_bit_cast(h2, A.w);
                const h2 vB0 = __builtin_bit_cast(h2, B.z);
                const h2 vB1 = __builtin_bit_cast(h2, B.w);
                ctx[0] = fmaf(p, (float)vA0.x, ctx[0]);
                ctx[1] = fmaf(p, (float)vA0.y, ctx[1]);
                ctx[2] = fmaf(p, (float)vA1.x, ctx[2]);
                ctx[3] = fmaf(p, (float)vA1.y, ctx[3]);
                ctx[4] = fmaf(p, (float)vB0.x, ctx[4]);
                ctx[5] = fmaf(p, (float)vB0.y, ctx[5]);
                ctx[6] = fmaf(p, (float)vB1.x, ctx[6]);
                ctx[7] = fmaf(p, (float)vB1.y, ctx[7]);
            }
        } else {
            // ---- rare fallback: accumulate only (attn written in pass 2) ----
            for (int base = e0; base < e1; base += 64) {
                const int c2 = min(64, e1 - base);
                int sid = 0;
                if (base + lane < e1) sid = senders[base + lane];
                const int it2 = (c2 + 7) >> 3;
                for (int i = 0; i < it2; ++i) {
                    const int idx = i * 8 + g;
                    const int s = __shfl(sid, idx, 64);
                    const unsigned char* row = packed + (size_t)s * 256 + u * 32;
                    const uint4 A = *(const uint4*)(row);
                    const uint4 B = *(const uint4*)(row + 16);
                    float d = __builtin_amdgcn_fdot2(q0, __builtin_bit_cast(h2, A.x), 0.f, false);
                    d = __builtin_amdgcn_fdot2(q1, __builtin_bit_cast(h2, A.y), d, false);
                    d = __builtin_amdgcn_fdot2(q2, __builtin_bit_cast(h2, B.x), d, false);
                    d = __builtin_amdgcn_fdot2(q3, __builtin_bit_cast(h2, B.y), d, false);
                    d += __shfl_xor(d, 1, 64);
                    float p = __expf(d);
                    p = (idx < c2) ? p : 0.f;
                    l += p;
                    const h2 vA0 = __builtin_bit_cast(h2, A.z);
                    const h2 vA1 = __builtin_bit_cast(h2, A.w);
                    const h2 vB0 = __builtin_bit_cast(h2, B.z);
                    const h2 vB1 = __builtin_bit_cast(h2, B.w);
                    ctx[0] = fmaf(p, (float)vA0.x, ctx[0]);
                    ctx[1] = fmaf(p, (float)vA0.y, ctx[1]);
                    ctx[2] = fmaf(p, (float)vA1.x, ctx[2]);
                    ctx[3] = fmaf(p, (float)vA1.y, ctx[3]);
                    ctx[4] = fmaf(p, (float)vB0.x, ctx[4]);
                    ctx[5] = fmaf(p, (float)vB0.y, ctx[5]);
                    ctx[6] = fmaf(p, (float)vB1.x, ctx[6]);
                    ctx[7] = fmaf(p, (float)vB1.y, ctx[7]);
                }
            }
        }

        // Merge the 8 edge-group partials (butterfly -> all lanes merged).
#pragma unroll
        for (int mask = 8; mask <= 32; mask <<= 1) {
            l += __shfl_xor(l, mask, 64);
#pragma unroll
            for (int j = 0; j < 8; ++j)
                ctx[j] += __shfl_xor(ctx[j], mask, 64);
        }
        const float inv = (l > 0.f) ? (1.f / l) : 0.f;

        if (cnt <= 64) {
            // Normalized attn from registers: lane (u even) = head u>>1.
            if ((u & 1) == 0) {
                const int h = u >> 1;
#pragma unroll
                for (int i = 0; i < 8; ++i) {
                    const int idx = i * 8 + g;
                    if (i < iters && idx < cnt)
                        attn_out[(size_t)(e0 + idx) * 4 + h] = preg[i] * inv;
                }
            }
        } else {
            // Pass 2 (rare): recompute scores, write normalized attn.
            for (int base = e0; base < e1; base += 64) {
                const int c2 = min(64, e1 - base);
                int sid = 0;
                if (base + lane < e1) sid = senders[base + lane];
                const int it2 = (c2 + 7) >> 3;
                for (int i = 0; i < it2; ++i) {
                    const int idx = i * 8 + g;
                    const int s = __shfl(sid, idx, 64);
                    if (idx < c2) {
                        const unsigned char* row = packed + (size_t)s * 256 + u * 32;
                        const uint4 A = *(const uint4*)(row);
                        const uint4 B = *(const uint4*)(row + 16);
                        float d = __builtin_amdgcn_fdot2(q0, __builtin_bit_cast(h2, A.x), 0.f, false);
                        d = __builtin_amdgcn_fdot2(q1, __builtin_bit_cast(h2, A.y), d, false);
                        d = __builtin_amdgcn_fdot2(q2, __builtin_bit_cast(h2, B.x), d, false);
                        d = __builtin_amdgcn_fdot2(q3, __builtin_bit_cast(h2, B.y), d, false);
                        d += __shfl_xor(d, 1, 64);
                        const float p = __expf(d);
                        if ((u & 1) == 0)
                            attn_out[(size_t)(base + idx) * 4 + (u >> 1)] = p * inv;
                    }
                }
            }
        }

        // Normalized context -> wave-private LDS (lanes of group 0 hold full
        // sums after the butterfly; channels 8u..8u+7 -> sCtx[u*8..u*8+7]).
        if (g == 0) {
            *(float4*)(&sCtx[wave][u * 8]) =
                make_float4(ctx[0] * inv, ctx[1] * inv, ctx[2] * inv, ctx[3] * inv);
            *(float4*)(&sCtx[wave][u * 8 + 4]) =
                make_float4(ctx[4] * inv, ctx[5] * inv, ctx[6] * inv, ctx[7] * inv);
        }

        // Epilogue: out[n][lane] = bout[lane] + sum_k ctx[k]*Wout[k][lane].
        float acc = bo;
#pragma unroll
        for (int k = 0; k < 64; k += 4) {
            const float4 c = *(const float4*)(&sCtx[wave][k]);
            acc = fmaf(c.x, sW[(k + 0) * 64 + lane], acc);
            acc = fmaf(c.y, sW[(k + 1) * 64 + lane], acc);
            acc = fmaf(c.z, sW[(k + 2) * 64 + lane], acc);
            acc = fmaf(c.w, sW[(k + 3) * 64 + lane], acc);
        }
        out[(size_t)n * 64 + lane] = acc;
    }
}

// ---------------------------------------------------------------------------
extern "C" void kernel_launch(void* const* d_in, const int* in_sizes, int n_in,
                              void* d_out, int out_size, void* d_ws, size_t ws_size,
                              hipStream_t stream) {
    const float* nodes   = (const float*)d_in[0];
    const float* W_qk    = (const float*)d_in[1];
    const float* b_qk    = (const float*)d_in[2];
    const float* W_v     = (const float*)d_in[3];
    const float* b_v     = (const float*)d_in[4];
    const float* W_out   = (const float*)d_in[5];
    const float* b_out   = (const float*)d_in[6];
    const int* senders   = (const int*)d_in[7];
    const int* receivers = (const int*)d_in[8];

    const int N = in_sizes[0] / 64;  // 100000
    const int E = in_sizes[7];       // 1000000

    float* out      = (float*)d_out;
    float* attn_out = out + (size_t)N * 64;

    // Workspace layout kept from previous rounds (p_ws region now unused):
    // packed fp16 q|v (25.6MB) | rowptr | [unused 16MB] | Wt (16KB)
    unsigned char* packed = (unsigned char*)d_ws;
    int*   rowp = (int*)(packed + (size_t)N * 256);
    float* p_ws = (float*)(rowp + (((N + 1) + 3) & ~3));
    _Float16* Wt = (_Float16*)(p_ws + (size_t)E * 4);

    const int RB = (N + 1 + 255) / 256;       // rowptr blocks
    mhga_prep<<<32 + RB, 256, 0, stream>>>(W_qk, W_v, Wt, receivers, rowp, N, E);
    mhga_proj<<<(N + 63) / 64, 256, 0, stream>>>(nodes, Wt, b_qk, b_v,
                                                 packed, N);
    // Persistent: 2048 blocks = 8 blocks/CU; waves grid-stride independently.
    mhga_attn<<<2048, 256, 0, stream>>>(packed, senders, rowp,
                                        W_out, b_out, out, attn_out, N);
}

// Round 2
// 190.956 us; speedup vs baseline: 1.1216x; 1.1216x over previous
//
#include <hip/hip_runtime.h>
#include <math.h>

// N=100000 nodes, E=1000000 edges, D_IN=64, D_MODEL=64, H=4 x D=16.
// Packed node layout: per node, 16 chunks of 16 B; chunk c = bytes [16c,16c+16)
//   = { q[4c..4c+3] fp16 (8 B) | v[4c..4c+3] fp16 (8 B) }. Row = 256 B.

typedef _Float16 h2 __attribute__((ext_vector_type(2)));
typedef _Float16 half8 __attribute__((ext_vector_type(8)));
typedef float floatx4 __attribute__((ext_vector_type(4)));

#define SP_ROW 136  // fp16 per LDS row (272 B): +8 pad breaks pow-2 bank stride

// ---------------------------------------------------------------------------
// Kernel 0: prep. Blocks [0,32): Wt[n][k] = fp16 W[k][n] (n<64 -> Wqk col n,
// else Wv col n-64). Blocks [32,..): CSR rowptr binary search.  (UNCHANGED)
__global__ __launch_bounds__(256) void mhga_prep(
    const float* __restrict__ Wqk, const float* __restrict__ Wv,
    _Float16* __restrict__ Wt,
    const int* __restrict__ receivers, int* __restrict__ row_ptr,
    int N, int E)
{
    if ((int)blockIdx.x < 32) {
        const int idx = blockIdx.x * 256 + threadIdx.x;   // 0..8191
        const int n = idx >> 6, k = idx & 63;
        const float w = (n < 64) ? Wqk[k * 64 + n] : Wv[k * 64 + (n - 64)];
        Wt[idx] = (_Float16)w;
        return;
    }
    const int n = (blockIdx.x - 32) * 256 + threadIdx.x;
    if (n > N) return;
    int lo = 0, hi = E;
    while (lo < hi) {
        const int mid = (lo + hi) >> 1;
        if (receivers[mid] < n) lo = mid + 1; else hi = mid;
    }
    row_ptr[n] = lo;
}

// ---------------------------------------------------------------------------
// Kernel 1: MFMA fp16 projection -> packed fp16 q|v rows.  (UNCHANGED — control)
__global__ __launch_bounds__(256) void mhga_proj(
    const float* __restrict__ X, const _Float16* __restrict__ Wt,
    const float* __restrict__ bqk, const float* __restrict__ bv,
    unsigned char* __restrict__ packed, int N)
{
    __shared__ __align__(16) _Float16 sP[64 * SP_ROW];   // 17 KB repack tile
    const int t = threadIdx.x;
    const int w = t >> 6, lane = t & 63;
    const int ln = lane & 15, quad = lane >> 4;
    const int m0 = blockIdx.x * 64;

    // A fragments: A[m=ln][k=quad*8+j], k-halves 0 / 32. Direct f32 loads.
    const int arow = min(m0 + w * 16 + ln, N - 1);
    const float* xr = X + (size_t)arow * 64;
    const float4 xa = *(const float4*)(xr + quad * 8);
    const float4 xb = *(const float4*)(xr + quad * 8 + 4);
    const float4 xc = *(const float4*)(xr + 32 + quad * 8);
    const float4 xd = *(const float4*)(xr + 32 + quad * 8 + 4);
    const half8 a0 = { (_Float16)xa.x, (_Float16)xa.y, (_Float16)xa.z,
                       (_Float16)xa.w, (_Float16)xb.x, (_Float16)xb.y,
                       (_Float16)xb.z, (_Float16)xb.w };
    const half8 a1 = { (_Float16)xc.x, (_Float16)xc.y, (_Float16)xc.z,
                       (_Float16)xc.w, (_Float16)xd.x, (_Float16)xd.y,
                       (_Float16)xd.z, (_Float16)xd.w };

    // 8 output tiles: B[k][n], lane&15 = n-within-tile, k = quad*8+j.
    floatx4 acc[8];
#pragma unroll
    for (int tt = 0; tt < 8; ++tt) {
        const _Float16* wrow = Wt + (tt * 16 + ln) * 64;
        const half8 b0 = *(const half8*)(wrow + quad * 8);
        const half8 b1 = *(const half8*)(wrow + 32 + quad * 8);
        floatx4 c = {0.f, 0.f, 0.f, 0.f};
        c = __builtin_amdgcn_mfma_f32_16x16x32_f16(a0, b0, c, 0, 0, 0);
        c = __builtin_amdgcn_mfma_f32_16x16x32_f16(a1, b1, c, 0, 0, 0);
        acc[tt] = c;
    }

    // Repack: D row = quad*4+reg, col j = tt*16+ln. q col j -> fp16 idx
    // (j>>2)*8 + (j&3); v col j -> (j>>2)*8 + 4 + (j&3).
#pragma unroll
    for (int tt = 0; tt < 8; ++tt) {
        const float bt = (tt < 4) ? bqk[tt * 16 + ln] : bv[(tt - 4) * 16 + ln];
        const int j = (tt & 3) * 16 + ln;
        const int fidx = (j >> 2) * 8 + ((tt < 4) ? 0 : 4) + (j & 3);
#pragma unroll
        for (int r = 0; r < 4; ++r) {
            const int lrow = w * 16 + quad * 4 + r;
            sP[lrow * SP_ROW + fidx] = (_Float16)(acc[tt][r] + bt);
        }
    }

    // Wave-local coalesced copy: lane lt -> row w*16+(lt>>2), 64-B segment
    // (lt&3). In-order DS completion + compiler lgkmcnt ordering make the
    // write->read dependency safe within the wave (no barrier).
    const int crow = w * 16 + (lane >> 2);
    const int grow = m0 + crow;
    if (grow < N) {
        const _Float16* src = sP + crow * SP_ROW + (lane & 3) * 32;
        unsigned char* dst = packed + (size_t)grow * 256 + (lane & 3) * 64;
#pragma unroll
        for (int c = 0; c < 4; ++c)
            *(uint4*)(dst + c * 16) = *(const uint4*)(src + c * 8);
    }
}

// ---------------------------------------------------------------------------
// Kernel 2: fused attention + output projection.
// Round-2: round-0 lane geometry restored (16 lanes/edge, 4 edge-groups,
// VGPR ~24 -> 8 waves/SIMD) — round-1's 8x8 layout blew VGPR to 76 and
// collapsed occupancy 72%->28%. Single-pass softmax KEPT, but p is staged in
// a 1 KB/wave LDS buffer (sAtt) instead of a 16 MB global: no p_ws traffic,
// no per-lap vmcnt(0) drain, no volatile L1-bypass reload. Hot loop is
// branch-free (clamped sid, cndmask p). deg>64 fallback (never taken for
// this data: Poisson(10), max deg ~30) writes raw p to attn_out and
// normalizes in place with the old drain+volatile trick.
__global__ __launch_bounds__(256) void mhga_attn(
    const unsigned char* __restrict__ packed,
    const int* __restrict__ senders, const int* __restrict__ row_ptr,
    const float* __restrict__ Wout, const float* __restrict__ bout,
    float* __restrict__ out, float* __restrict__ attn_out, int N)
{
    __shared__ float sW[64 * 64];    // Wout[k][j]               (16 KB)
    __shared__ float sCtx[4][64];    // per-wave normalized ctx  (1 KB)
    __shared__ float sAtt[4][256];   // per-wave p stage: 64 edges x 4 heads (4 KB)
    const int t = threadIdx.x;
#pragma unroll
    for (int i = t * 4; i < 4096; i += 1024)
        *(float4*)(sW + i) = *(const float4*)(Wout + i);

    const int wave = t >> 6, lane = t & 63;
    const int g = lane >> 4, tl = lane & 15;   // edge-group, channel-lane
    const float bo = bout[lane];
    __syncthreads();   // the ONLY block-wide barrier

    for (int n = blockIdx.x * 4 + wave; n < N; n += gridDim.x * 4) {
        const int e0 = row_ptr[n];
        const int e1 = row_ptr[n + 1];
        const int cnt = e1 - e0;

        float l = 0.f;
        float4 ctx = make_float4(0.f, 0.f, 0.f, 0.f);
        const uint4 qpk = *(const uint4*)(packed + (size_t)n * 256 + tl * 16);
        const h2 q0 = __builtin_bit_cast(h2, qpk.x);
        const h2 q1 = __builtin_bit_cast(h2, qpk.y);

        if (cnt <= 64) {
            // ---- hot path: one 64-edge chunk, p staged in wave-local LDS ----
            int sid = 0;
            if (e0 + lane < e1) sid = senders[e0 + lane];   // coalesced
            const int iters = (cnt + 3) >> 2;
            for (int i = 0; i < iters; ++i) {
                const int idx = i * 4 + g;          // this group's edge
                const int s = __shfl(sid, idx, 64); // row 0 for tail slots
                const uint4 pk =
                    *(const uint4*)(packed + (size_t)s * 256 + tl * 16);
                const h2 k0 = __builtin_bit_cast(h2, pk.x);
                const h2 k1 = __builtin_bit_cast(h2, pk.y);
                const h2 v0 = __builtin_bit_cast(h2, pk.z);
                const h2 v1 = __builtin_bit_cast(h2, pk.w);
                float d = __builtin_amdgcn_fdot2(q0, k0, 0.f, false);
                d = __builtin_amdgcn_fdot2(q1, k1, d, false);
                d += __shfl_xor(d, 1, 64);          // head-group reduce
                d += __shfl_xor(d, 2, 64);
                float p = __expf(d);
                p = (idx < cnt) ? p : 0.f;          // cndmask, no branch
                if ((tl & 3) == 0)
                    sAtt[wave][idx * 4 + (tl >> 2)] = p;   // conflict-free
                l += p;
                ctx.x = fmaf(p, (float)v0.x, ctx.x);
                ctx.y = fmaf(p, (float)v0.y, ctx.y);
                ctx.z = fmaf(p, (float)v1.x, ctx.z);
                ctx.w = fmaf(p, (float)v1.y, ctx.w);
            }
        } else {
            // ---- rare fallback: raw p -> attn_out, normalize in place ----
            for (int base = e0; base < e1; base += 64) {
                const int c2 = min(64, e1 - base);
                int sid = 0;
                if (base + lane < e1) sid = senders[base + lane];
                const int it2 = (c2 + 3) >> 2;
                for (int i = 0; i < it2; ++i) {
                    const int idx = i * 4 + g;
                    const int s = __shfl(sid, idx, 64);
                    if (idx < c2) {
                        const uint4 pk =
                            *(const uint4*)(packed + (size_t)s * 256 + tl * 16);
                        const h2 k0 = __builtin_bit_cast(h2, pk.x);
                        const h2 k1 = __builtin_bit_cast(h2, pk.y);
                        const h2 v0 = __builtin_bit_cast(h2, pk.z);
                        const h2 v1 = __builtin_bit_cast(h2, pk.w);
                        float d = __builtin_amdgcn_fdot2(q0, k0, 0.f, false);
                        d = __builtin_amdgcn_fdot2(q1, k1, d, false);
                        d += __shfl_xor(d, 1, 64);
                        d += __shfl_xor(d, 2, 64);
                        const float p = __expf(d);
                        if ((tl & 3) == 0)
                            attn_out[(size_t)(base + idx) * 4 + (tl >> 2)] = p;
                        l += p;
                        ctx.x = fmaf(p, (float)v0.x, ctx.x);
                        ctx.y = fmaf(p, (float)v0.y, ctx.y);
                        ctx.z = fmaf(p, (float)v1.x, ctx.z);
                        ctx.w = fmaf(p, (float)v1.y, ctx.w);
                    }
                }
            }
        }

        // Sum the 4 edge-group partials (butterfly -> all lanes merged).
#pragma unroll
        for (int mask = 16; mask <= 32; mask <<= 1) {
            l     += __shfl_xor(l, mask, 64);
            ctx.x += __shfl_xor(ctx.x, mask, 64);
            ctx.y += __shfl_xor(ctx.y, mask, 64);
            ctx.z += __shfl_xor(ctx.z, mask, 64);
            ctx.w += __shfl_xor(ctx.w, mask, 64);
        }
        const float inv = (l > 0.f) ? (1.f / l) : 0.f;
        if (g == 0) {
            *(float4*)(&sCtx[wave][tl * 4]) =
                make_float4(ctx.x * inv, ctx.y * inv, ctx.z * inv, ctx.w * inv);
        }

        // Pass B: attn = p / l[head], head = f&3 = lane&3 (stride 64).
        const float lh = __shfl(l, (lane & 3) << 2, 64);
        const float invl = (lh > 0.f) ? (1.f / lh) : 0.f;
        if (cnt <= 64) {
            const int cnt4 = cnt * 4;
            for (int f = lane; f < cnt4; f += 64)
                attn_out[e0 * 4 + f] = sAtt[wave][f] * invl;   // wave-local LDS
        } else {
            // Drain our raw-p stores -> L2, then in-place normalize.
            __builtin_amdgcn_s_waitcnt(0x0F70);   // vmcnt(0)
            volatile const float* vp = attn_out;  // L1-bypass
            for (int f = e0 * 4 + lane; f < e1 * 4; f += 64)
                attn_out[f] = vp[f] * invl;
        }

        // Epilogue: out[n][lane] = bout[lane] + sum_k ctx[k]*Wout[k][lane].
        float acc = bo;
#pragma unroll
        for (int k = 0; k < 64; k += 4) {
            const float4 c = *(const float4*)(&sCtx[wave][k]);
            acc = fmaf(c.x, sW[(k + 0) * 64 + lane], acc);
            acc = fmaf(c.y, sW[(k + 1) * 64 + lane], acc);
            acc = fmaf(c.z, sW[(k + 2) * 64 + lane], acc);
            acc = fmaf(c.w, sW[(k + 3) * 64 + lane], acc);
        }
        out[(size_t)n * 64 + lane] = acc;
    }
}

// ---------------------------------------------------------------------------
extern "C" void kernel_launch(void* const* d_in, const int* in_sizes, int n_in,
                              void* d_out, int out_size, void* d_ws, size_t ws_size,
                              hipStream_t stream) {
    const float* nodes   = (const float*)d_in[0];
    const float* W_qk    = (const float*)d_in[1];
    const float* b_qk    = (const float*)d_in[2];
    const float* W_v     = (const float*)d_in[3];
    const float* b_v     = (const float*)d_in[4];
    const float* W_out   = (const float*)d_in[5];
    const float* b_out   = (const float*)d_in[6];
    const int* senders   = (const int*)d_in[7];
    const int* receivers = (const int*)d_in[8];

    const int N = in_sizes[0] / 64;  // 100000
    const int E = in_sizes[7];       // 1000000

    float* out      = (float*)d_out;
    float* attn_out = out + (size_t)N * 64;

    // Workspace layout kept from previous rounds (p_ws region now unused):
    // packed fp16 q|v (25.6MB) | rowptr | [unused 16MB] | Wt (16KB)
    unsigned char* packed = (unsigned char*)d_ws;
    int*   rowp = (int*)(packed + (size_t)N * 256);
    float* p_ws = (float*)(rowp + (((N + 1) + 3) & ~3));
    _Float16* Wt = (_Float16*)(p_ws + (size_t)E * 4);

    const int RB = (N + 1 + 255) / 256;       // rowptr blocks
    mhga_prep<<<32 + RB, 256, 0, stream>>>(W_qk, W_v, Wt, receivers, rowp, N, E);
    mhga_proj<<<(N + 63) / 64, 256, 0, stream>>>(nodes, Wt, b_qk, b_v,
                                                 packed, N);
    // Persistent: 1792 blocks = 7 blocks/CU (LDS 21.5 KB -> 7 resident);
    // waves grid-stride independently.
    mhga_attn<<<1792, 256, 0, stream>>>(packed, senders, rowp,
                                        W_out, b_out, out, attn_out, N);
}